// Round 5
// baseline (1773.706 us; speedup 1.0000x reference)
//
#include <hip/hip_runtime.h>
#include <hip/hip_bf16.h>
#include <stdint.h>

#define B_   64
#define S_   512
#define IN_  256
#define H_   512
#define O_   256

// k_rnn W_hh residency (64 k-groups of 8 cols, per output row):
//   groups  0..31 -> AGPR (2 rows/thread = 256 AGPRs, forced via inline asm)
//   groups 32..51 -> arch VGPR (2 x 20 quads = 160 regs)
//   groups 52..60 -> LDS (9 x 8KB = 73.7KB)
//   groups 61..63 -> streamed from L2 each step
#define AGQ 32
#define RVQ 20
#define LGQ 9
#define SGQ 3

typedef _Float16 h16;
typedef __attribute__((ext_vector_type(2))) _Float16 half2v;

static __device__ __forceinline__ float fdot2(uint32_t w, uint32_t h, float acc) {
#if __has_builtin(__builtin_amdgcn_fdot2)
  return __builtin_amdgcn_fdot2(__builtin_bit_cast(half2v, w),
                                __builtin_bit_cast(half2v, h), acc, false);
#else
  half2v a = __builtin_bit_cast(half2v, w), b = __builtin_bit_cast(half2v, h);
  return acc + (float)a[0] * (float)b[0] + (float)a[1] * (float)b[1];
#endif
}

static __device__ __forceinline__ uint32_t pack2(float a, float b) {
  h16 lo = (h16)a, hi = (h16)b;
  uint32_t u = (uint32_t)__builtin_bit_cast(unsigned short, lo);
  uint32_t v = (uint32_t)__builtin_bit_cast(unsigned short, hi);
  return u | (v << 16);
}

static __device__ __forceinline__ float fast_tanh(float x) {
#if __has_builtin(__builtin_amdgcn_exp2f) && __has_builtin(__builtin_amdgcn_rcpf)
  float xc = fminf(9.0f, fmaxf(-9.0f, x));
  float e2 = __builtin_amdgcn_exp2f(xc * 2.8853900817779268f);  // e^{2x}
  return (e2 - 1.0f) * __builtin_amdgcn_rcpf(e2 + 1.0f);
#else
  return tanhf(x);
#endif
}

// ---------------- packing kernels (f32 -> f16x2 dwords) ----------------

__global__ void k_pack_x(const float2* __restrict__ x2, uint32_t* __restrict__ xpk, int n) {
  int i = blockIdx.x * blockDim.x + threadIdx.x;
  int stride = gridDim.x * blockDim.x;
  for (; i < n; i += stride) { float2 v = x2[i]; xpk[i] = pack2(v.x, v.y); }
}

// W_ih (H,IN) -> [k2][n] dwords
__global__ void k_pack_wih(const float* __restrict__ w, uint32_t* __restrict__ wp) {
  int i = blockIdx.x * 256 + threadIdx.x;   // 65536
  int k2 = i >> 9, n = i & 511;
  wp[i] = pack2(w[n * IN_ + 2 * k2], w[n * IN_ + 2 * k2 + 1]);
}

// W_ff (O,H) -> [k2][o] dwords
__global__ void k_pack_wff(const float* __restrict__ w, uint32_t* __restrict__ wp) {
  int i = blockIdx.x * 256 + threadIdx.x;   // 65536
  int k2 = i >> 8, o = i & 255;
  wp[i] = pack2(w[o * H_ + 2 * k2], w[o * H_ + 2 * k2 + 1]);
}

// W_hh (H,H) -> uint4 quads: [g][o], g=k/8 in [0,64), o in [0,512)
__global__ void k_pack_whh(const float* __restrict__ w, uint32_t* __restrict__ wp) {
  int i = blockIdx.x * 256 + threadIdx.x;   // 131072 dwords
  int g = i >> 11, o = (i >> 2) & 511, c = i & 3;
  int k = 8 * g + 2 * c;
  wp[i] = pack2(w[o * H_ + k], w[o * H_ + k + 1]);
}

// ---------------- tiled fdot2 GEMM (unchanged) ----------------

template <int NSTAGES, bool OUT16>
__global__ void __launch_bounds__(256) k_gemm(
    const uint32_t* __restrict__ apack, const uint32_t* __restrict__ wpack,
    const float* __restrict__ bias0, const float* __restrict__ bias1,
    void* __restrict__ outp, int Ncols)
{
  const int K2 = NSTAGES * 64;
  __shared__ uint32_t xs[128][65];
  __shared__ uint32_t ws[64][64];
  const int tid = threadIdx.x;
  const int mbase = blockIdx.x * 128;
  const int nbase = blockIdx.y * 64;
  const int tx = tid & 7, ty = tid >> 3;
  const int m0 = ty * 4, n0 = tx * 8;

  float bs[8];
#pragma unroll
  for (int j = 0; j < 8; ++j) {
    int n = nbase + n0 + j;
    bs[j] = bias0[n] + (bias1 ? bias1[n] : 0.0f);
  }

  float acc[4][8];
#pragma unroll
  for (int i = 0; i < 4; ++i)
#pragma unroll
    for (int j = 0; j < 8; ++j) acc[i][j] = 0.0f;

  for (int s = 0; s < NSTAGES; ++s) {
    const int k2b = s * 64;
    __syncthreads();
#pragma unroll
    for (int c = 0; c < 32; ++c) {
      int idx = c * 256 + tid;
      int m = idx >> 6, k2 = idx & 63;
      xs[m][k2] = apack[(size_t)(mbase + m) * K2 + k2b + k2];
    }
#pragma unroll
    for (int c = 0; c < 16; ++c) {
      int idx = c * 256 + tid;
      int k2 = idx >> 6, n = idx & 63;
      ws[k2][n] = wpack[(size_t)(k2b + k2) * Ncols + nbase + n];
    }
    __syncthreads();
#pragma unroll 8
    for (int k2 = 0; k2 < 64; ++k2) {
      uint32_t xv[4];
#pragma unroll
      for (int i = 0; i < 4; ++i) xv[i] = xs[m0 + i][k2];
      uint4 wA = *(const uint4*)&ws[k2][n0];
      uint4 wB = *(const uint4*)&ws[k2][n0 + 4];
#pragma unroll
      for (int i = 0; i < 4; ++i) {
        acc[i][0] = fdot2(xv[i], wA.x, acc[i][0]);
        acc[i][1] = fdot2(xv[i], wA.y, acc[i][1]);
        acc[i][2] = fdot2(xv[i], wA.z, acc[i][2]);
        acc[i][3] = fdot2(xv[i], wA.w, acc[i][3]);
        acc[i][4] = fdot2(xv[i], wB.x, acc[i][4]);
        acc[i][5] = fdot2(xv[i], wB.y, acc[i][5]);
        acc[i][6] = fdot2(xv[i], wB.z, acc[i][6]);
        acc[i][7] = fdot2(xv[i], wB.w, acc[i][7]);
      }
    }
  }
  if constexpr (OUT16) {
    uint32_t* o16 = (uint32_t*)outp;
    const int ncd = Ncols >> 1;
#pragma unroll
    for (int i = 0; i < 4; ++i) {
      size_t row = (size_t)(mbase + m0 + i) * ncd + ((nbase + n0) >> 1);
      uint4 pk;
      pk.x = pack2(acc[i][0] + bs[0], acc[i][1] + bs[1]);
      pk.y = pack2(acc[i][2] + bs[2], acc[i][3] + bs[3]);
      pk.z = pack2(acc[i][4] + bs[4], acc[i][5] + bs[5]);
      pk.w = pack2(acc[i][6] + bs[6], acc[i][7] + bs[7]);
      *(uint4*)&o16[row] = pk;
    }
  } else {
    float* out = (float*)outp;
#pragma unroll
    for (int i = 0; i < 4; ++i) {
      size_t row = (size_t)(mbase + m0 + i) * Ncols + nbase + n0;
      float4 r0 = make_float4(acc[i][0] + bs[0], acc[i][1] + bs[1],
                              acc[i][2] + bs[2], acc[i][3] + bs[3]);
      float4 r1 = make_float4(acc[i][4] + bs[4], acc[i][5] + bs[5],
                              acc[i][6] + bs[6], acc[i][7] + bs[7]);
      *(float4*)&out[row] = r0;
      *(float4*)&out[row + 4] = r1;
    }
  }
}

// ---------------- persistent recurrence ----------------
// 64 blocks x 256 threads (4 waves = 1 wave/EU: 256 arch VGPRs granted [R3]
// + 256 AGPRs = full 512-reg/wave unified file).
// Thread t owns rows t and t+256.

#define DOT4(W, HH, A0, A1, A2, A3)               \
  { A0 = fdot2((W).x, (HH).x, A0);                \
    A1 = fdot2((W).y, (HH).y, A1);                \
    A2 = fdot2((W).z, (HH).z, A2);                \
    A3 = fdot2((W).w, (HH).w, A3); }

#define AG_EACH(X) X(0) X(1) X(2) X(3) X(4) X(5) X(6) X(7) X(8) X(9) \
  X(10) X(11) X(12) X(13) X(14) X(15) X(16) X(17) X(18) X(19) \
  X(20) X(21) X(22) X(23) X(24) X(25) X(26) X(27) X(28) X(29) X(30) X(31)

#define AG_DECL(i) uint32_t aAx_##i, aAy_##i, aAz_##i, aAw_##i, \
                            aBx_##i, aBy_##i, aBz_##i, aBw_##i;

#define AG_LOAD(i) { \
  uint4 v = wq[(size_t)(i) * H_ + t]; \
  uint4 u = wq[(size_t)(i) * H_ + t + 256]; \
  asm volatile("v_accvgpr_write_b32 %0, %1" : "=a"(aAx_##i) : "v"(v.x)); \
  asm volatile("v_accvgpr_write_b32 %0, %1" : "=a"(aAy_##i) : "v"(v.y)); \
  asm volatile("v_accvgpr_write_b32 %0, %1" : "=a"(aAz_##i) : "v"(v.z)); \
  asm volatile("v_accvgpr_write_b32 %0, %1" : "=a"(aAw_##i) : "v"(v.w)); \
  asm volatile("v_accvgpr_write_b32 %0, %1" : "=a"(aBx_##i) : "v"(u.x)); \
  asm volatile("v_accvgpr_write_b32 %0, %1" : "=a"(aBy_##i) : "v"(u.y)); \
  asm volatile("v_accvgpr_write_b32 %0, %1" : "=a"(aBz_##i) : "v"(u.z)); \
  asm volatile("v_accvgpr_write_b32 %0, %1" : "=a"(aBw_##i) : "v"(u.w)); }

#define AG_DOT(i) { \
  uint4 hv = h4[i]; \
  uint32_t p0, p1, p2, p3; \
  asm volatile("v_accvgpr_read_b32 %0, %1" : "=v"(p0) : "a"(aAx_##i)); \
  asm volatile("v_accvgpr_read_b32 %0, %1" : "=v"(p1) : "a"(aAy_##i)); \
  asm volatile("v_accvgpr_read_b32 %0, %1" : "=v"(p2) : "a"(aAz_##i)); \
  asm volatile("v_accvgpr_read_b32 %0, %1" : "=v"(p3) : "a"(aAw_##i)); \
  acc0 = fdot2(p0, hv.x, acc0); acc1 = fdot2(p1, hv.y, acc1); \
  acc2 = fdot2(p2, hv.z, acc2); acc3 = fdot2(p3, hv.w, acc3); \
  asm volatile("v_accvgpr_read_b32 %0, %1" : "=v"(p0) : "a"(aBx_##i)); \
  asm volatile("v_accvgpr_read_b32 %0, %1" : "=v"(p1) : "a"(aBy_##i)); \
  asm volatile("v_accvgpr_read_b32 %0, %1" : "=v"(p2) : "a"(aBz_##i)); \
  asm volatile("v_accvgpr_read_b32 %0, %1" : "=v"(p3) : "a"(aBw_##i)); \
  c0 = fdot2(p0, hv.x, c0); c1 = fdot2(p1, hv.y, c1); \
  c2 = fdot2(p2, hv.z, c2); c3 = fdot2(p3, hv.w, c3); }

__global__ __attribute__((amdgpu_flat_work_group_size(256, 256),
                          amdgpu_waves_per_eu(1, 1)))
void k_rnn(
    const uint4* __restrict__ wq,     // [64][512] uint4 (k-group x output-row)
    const h16* __restrict__ xp,       // [B*S][H] f16
    const float* __restrict__ h0,     // [B][H] f32
    h16* __restrict__ hs)             // [B*S][H] f16
{
  __shared__ uint4 lw[LGQ * H_];      // LDS-resident W groups: 73.7KB
  __shared__ uint4 hq[2][H_ / 8];     // double-buffered h (2 x 1KB)
  const int t = threadIdx.x;          // 0..255
  const int b = blockIdx.x;
  const int r1 = t + 256;

  AG_EACH(AG_DECL)
  AG_EACH(AG_LOAD)

  uint4 wrA[RVQ], wrB[RVQ];
#pragma unroll
  for (int g = 0; g < RVQ; ++g) {
    wrA[g] = wq[(size_t)(AGQ + g) * H_ + t];
    wrB[g] = wq[(size_t)(AGQ + g) * H_ + r1];
  }
  for (int i = t; i < LGQ * H_; i += 256) lw[i] = wq[(size_t)(AGQ + RVQ) * H_ + i];
  ((unsigned short*)&hq[0][0])[t] =
      __builtin_bit_cast(unsigned short, (h16)h0[(size_t)b * H_ + t]);
  ((unsigned short*)&hq[0][0])[r1] =
      __builtin_bit_cast(unsigned short, (h16)h0[(size_t)b * H_ + r1]);

  const uint4* wqs = wq + (size_t)(AGQ + RVQ + LGQ) * H_;   // stream groups
  const h16* xpb = xp + (size_t)b * S_ * H_;
  h16* hsb = hs + (size_t)b * S_ * H_;
  __syncthreads();

#pragma unroll 1
  for (int step = 0; step < S_; ++step) {
    const uint4* h4 = hq[step & 1];
    float xv0 = (float)xpb[(size_t)step * H_ + t];
    float xv1 = (float)xpb[(size_t)step * H_ + r1];
    float acc0 = 0.f, acc1 = 0.f, acc2 = 0.f, acc3 = 0.f;
    float c0 = 0.f, c1 = 0.f, c2 = 0.f, c3 = 0.f;
    uint4 sA[SGQ], sB[SGQ];
#pragma unroll
    for (int j = 0; j < SGQ; ++j) {       // issue L2 stream early (coalesced)
      sA[j] = wqs[(size_t)j * H_ + t];
      sB[j] = wqs[(size_t)j * H_ + r1];
    }
    AG_EACH(AG_DOT)                       // AGPR-resident W (groups 0..31)
#pragma unroll
    for (int g = 0; g < RVQ; ++g) {       // arch-VGPR-resident W (32..51)
      uint4 hv = h4[AGQ + g];
      DOT4(wrA[g], hv, acc0, acc1, acc2, acc3);
      DOT4(wrB[g], hv, c0, c1, c2, c3);
    }
#pragma unroll
    for (int j = 0; j < LGQ; ++j) {       // LDS-resident W (52..60)
      uint4 hv = h4[AGQ + RVQ + j];
      uint4 w0 = lw[j * H_ + t];
      uint4 w1 = lw[j * H_ + r1];
      DOT4(w0, hv, acc0, acc1, acc2, acc3);
      DOT4(w1, hv, c0, c1, c2, c3);
    }
#pragma unroll
    for (int j = 0; j < SGQ; ++j) {       // consume stream (61..63)
      uint4 hv = h4[AGQ + RVQ + LGQ + j];
      DOT4(sA[j], hv, acc0, acc1, acc2, acc3);
      DOT4(sB[j], hv, c0, c1, c2, c3);
    }
    float hn0 = fast_tanh(((acc0 + acc1) + (acc2 + acc3)) + xv0);
    float hn1 = fast_tanh(((c0 + c1) + (c2 + c3)) + xv1);
    h16 h016 = (h16)hn0, h116 = (h16)hn1;
    unsigned short* nb = (unsigned short*)&hq[(step + 1) & 1][0];
    nb[t]  = __builtin_bit_cast(unsigned short, h016);
    nb[r1] = __builtin_bit_cast(unsigned short, h116);
    hsb[(size_t)step * H_ + t]  = h016;
    hsb[(size_t)step * H_ + r1] = h116;
    __syncthreads();                      // next h ready
  }
}

// ---------------- host launch ----------------

extern "C" void kernel_launch(void* const* d_in, const int* in_sizes, int n_in,
                              void* d_out, int out_size, void* d_ws, size_t ws_size,
                              hipStream_t stream) {
  (void)in_sizes; (void)n_in; (void)out_size; (void)ws_size;
  const float* x   = (const float*)d_in[0];
  const float* h0  = (const float*)d_in[1];
  const float* Wih = (const float*)d_in[2];
  const float* Whh = (const float*)d_in[3];
  const float* bih = (const float*)d_in[4];
  const float* bhh = (const float*)d_in[5];
  const float* Wff = (const float*)d_in[6];
  const float* bff = (const float*)d_in[7];
  float* out = (float*)d_out;

  char* ws = (char*)d_ws;
  size_t off = 0;
  h16* xp16 = (h16*)(ws + off);           off += (size_t)B_ * S_ * H_ * 2;        // 33.5 MB
  uint32_t* xpk = (uint32_t*)(ws + off);  off += (size_t)B_ * S_ * (IN_ / 2) * 4; // 16.8 MB
  h16* hs = (h16*)(ws + off);             off += (size_t)B_ * S_ * H_ * 2;        // 33.5 MB
  uint32_t* whq = (uint32_t*)(ws + off);  off += (size_t)64 * H_ * 16;            // 0.5 MB
  uint32_t* wihp = (uint32_t*)(ws + off); off += (size_t)(IN_ / 2) * H_ * 4;
  uint32_t* wffp = (uint32_t*)(ws + off); off += (size_t)(H_ / 2) * O_ * 4;

  k_pack_x<<<2048, 256, 0, stream>>>((const float2*)x, xpk, B_ * S_ * (IN_ / 2));
  k_pack_wih<<<256, 256, 0, stream>>>(Wih, wihp);
  k_pack_whh<<<512, 256, 0, stream>>>(Whh, whq);
  k_pack_wff<<<256, 256, 0, stream>>>(Wff, wffp);

  // xp = x @ W_ih^T + b_ih + b_hh   (M=32768, N=512, K=256) -> f16 packed
  k_gemm<2, true><<<dim3(256, 8), 256, 0, stream>>>(xpk, wihp, bih, bhh, xp16, H_);
  // recurrence
  k_rnn<<<64, 256, 0, stream>>>((const uint4*)whq, xp16, h0, hs);
  // out = hs @ W_ff^T + b_ff        (M=32768, N=256, K=512) -> f32
  k_gemm<4, false><<<dim3(256, 4), 256, 0, stream>>>((const uint32_t*)hs, wffp, bff, nullptr, out, O_);
}